// Round 1
// baseline (109.628 us; speedup 1.0000x reference)
//
#include <hip/hip_runtime.h>

// MorphoMLP: y = relu(maxplus(relu(maxplus(x,W1)), W2)), all fp32.
// B=512, IN=512, HID=1024, OUT=512.
// Pipeline: [transpose3] -> [morpho L1, split-K=2, writes h^T partials] ->
//           [morpho L2, A = max(p0,p1,0) fused, split-K=4, writes y^T partials] ->
//           [combine: max over 4 partials + relu + transpose -> d_out]
// ws usage: 13 MB (xT 1MB | W1T 2MB | W2T 2MB | hp 4MB | yp 4MB)

#define WS_XT   0
#define WS_W1T  (512 * 512)
#define WS_W2T  (WS_W1T + 512 * 1024)
#define WS_HP   (WS_W2T + 1024 * 512)
#define WS_YP   (WS_HP + 2 * 1024 * 512)

// ---------------------------------------------------------------------------
// Fused transpose of x (512x512), W1 (1024x512), W2 (512x1024) into ws.
// 1280 blocks: [0,256) x | [256,768) W1 | [768,1280) W2.
__global__ __launch_bounds__(256) void transpose3(const float* __restrict__ x,
                                                  const float* __restrict__ W1,
                                                  const float* __restrict__ W2,
                                                  float* __restrict__ ws) {
    __shared__ float t[32][33];
    const int id = blockIdx.x;
    const float* src;
    float* dst;
    int R, C, rt, ct;
    if (id < 256) {
        src = x;  dst = ws + WS_XT;  R = 512;  C = 512;
        rt = id >> 4;          ct = id & 15;
    } else if (id < 768) {
        int b = id - 256;
        src = W1; dst = ws + WS_W1T; R = 1024; C = 512;
        rt = b >> 4;           ct = b & 15;
    } else {
        int b = id - 768;
        src = W2; dst = ws + WS_W2T; R = 512;  C = 1024;
        rt = b >> 5;           ct = b & 31;
    }
    const int tx = threadIdx.x & 31, ty = threadIdx.x >> 5;
    const int r0 = rt * 32, c0 = ct * 32;
#pragma unroll
    for (int r = 0; r < 4; r++)
        t[ty + 8 * r][tx] = src[(size_t)(r0 + ty + 8 * r) * C + c0 + tx];
    __syncthreads();
#pragma unroll
    for (int r = 0; r < 4; r++)
        dst[(size_t)(c0 + ty + 8 * r) * R + r0 + tx] = t[tx][ty + 8 * r];
}

// ---------------------------------------------------------------------------
// Max-plus tile kernel. A (K-major [K][512]) , W (K-major [K][Jdim]).
// Computes partial max over this block's K-chunk of (A[k][b] + W[k][j]),
// stores TRANSPOSED partial P[z][j][b] (raw max, no relu — combined later).
// AMAX: A element = max(A0[idx], A1[idx], 0)  (fuses L1 partial-combine+relu).
template <bool AMAX>
__global__ __launch_bounds__(256) void morpho(const float* __restrict__ A0,
                                              const float* __restrict__ A1,
                                              const float* __restrict__ W,
                                              float* __restrict__ P,
                                              int Jdim, int Kchunk) {
    __shared__ float lA[64 * 64];
    __shared__ float lW[64 * 64];
    const int t  = threadIdx.x;
    const int tx = t & 15;        // b-fragment selector (16 per wave row)
    const int ty = t >> 4;        // j-fragment selector (0..15 over block)
    const int j0 = blockIdx.x * 64;
    const int b0 = blockIdx.y * 64;
    const int k0 = blockIdx.z * Kchunk;

    float acc[4][4];  // acc[jj][i]: j = j0+ty*4+jj, b = b0+tx*4+i
#pragma unroll
    for (int jj = 0; jj < 4; jj++)
#pragma unroll
        for (int i = 0; i < 4; i++) acc[jj][i] = -3.402823466e38f;

    const float4* lA4 = (const float4*)lA;
    const float4* lW4 = (const float4*)lW;

    for (int sc = 0; sc < Kchunk; sc += 64) {
        // ---- stage 64 k-rows of A and W into LDS (direct copy, K-major) ----
#pragma unroll
        for (int r = 0; r < 4; r++) {
            const int q  = t + 256 * r;   // 0..1023 float4 slots
            const int kk = q >> 4;
            const int c  = q & 15;
            const int gk = k0 + sc + kk;
            float4 av;
            const float4* pa0 = (const float4*)(A0 + (size_t)gk * 512 + b0) + c;
            if (AMAX) {
                const float4* pa1 = (const float4*)(A1 + (size_t)gk * 512 + b0) + c;
                const float4 v0 = *pa0;
                const float4 v1 = *pa1;
                av.x = fmaxf(fmaxf(v0.x, v1.x), 0.0f);
                av.y = fmaxf(fmaxf(v0.y, v1.y), 0.0f);
                av.z = fmaxf(fmaxf(v0.z, v1.z), 0.0f);
                av.w = fmaxf(fmaxf(v0.w, v1.w), 0.0f);
            } else {
                av = *pa0;
            }
            ((float4*)lA)[kk * 16 + c] = av;
            ((float4*)lW)[kk * 16 + c] =
                *((const float4*)(W + (size_t)gk * Jdim + j0) + c);
        }
        __syncthreads();

        // ---- inner max-plus loop: 2 k's per iter so fmax pairs fuse to v_max3
#pragma unroll 4
        for (int kk = 0; kk < 64; kk += 2) {
            const float4 a0 = lA4[kk * 16 + tx];
            const float4 w0 = lW4[kk * 16 + ty];
            const float4 a1 = lA4[kk * 16 + 16 + tx];
            const float4 w1 = lW4[kk * 16 + 16 + ty];
#define UPD(JJ, W0C, W1C)                                                  \
    acc[JJ][0] = fmaxf(fmaxf(acc[JJ][0], a0.x + (W0C)), a1.x + (W1C));     \
    acc[JJ][1] = fmaxf(fmaxf(acc[JJ][1], a0.y + (W0C)), a1.y + (W1C));     \
    acc[JJ][2] = fmaxf(fmaxf(acc[JJ][2], a0.z + (W0C)), a1.z + (W1C));     \
    acc[JJ][3] = fmaxf(fmaxf(acc[JJ][3], a0.w + (W0C)), a1.w + (W1C));
            UPD(0, w0.x, w1.x)
            UPD(1, w0.y, w1.y)
            UPD(2, w0.z, w1.z)
            UPD(3, w0.w, w1.w)
#undef UPD
        }
        __syncthreads();
    }

    // ---- store transposed partial: P[z][j][b], float4 over b (coalesced) ----
    float* Pp = P + (size_t)blockIdx.z * Jdim * 512;
#pragma unroll
    for (int jj = 0; jj < 4; jj++) {
        const float4 v = make_float4(acc[jj][0], acc[jj][1], acc[jj][2], acc[jj][3]);
        *(float4*)(Pp + (size_t)(j0 + ty * 4 + jj) * 512 + b0 + tx * 4) = v;
    }
}

// ---------------------------------------------------------------------------
// Combine 4 y^T partials [o][b] -> max -> relu -> transpose -> d_out[b][o].
__global__ __launch_bounds__(256) void combine4(const float* __restrict__ yp,
                                                float* __restrict__ out) {
    __shared__ float t[32][33];
    const int id = blockIdx.x;
    const int ot = id & 15, bt = id >> 4;
    const int tx = threadIdx.x & 31, ty = threadIdx.x >> 5;
    const int o0 = ot * 32, b0 = bt * 32;
#pragma unroll
    for (int r = 0; r < 4; r++) {
        const int o   = o0 + ty + 8 * r;
        const int idx = o * 512 + b0 + tx;
        const float v0 = yp[idx];
        const float v1 = yp[idx + 512 * 512];
        const float v2 = yp[idx + 2 * 512 * 512];
        const float v3 = yp[idx + 3 * 512 * 512];
        t[ty + 8 * r][tx] = fmaxf(fmaxf(fmaxf(v0, v1), fmaxf(v2, v3)), 0.0f);
    }
    __syncthreads();
#pragma unroll
    for (int r = 0; r < 4; r++)
        out[(b0 + ty + 8 * r) * 512 + o0 + tx] = t[tx][ty + 8 * r];
}

// ---------------------------------------------------------------------------
extern "C" void kernel_launch(void* const* d_in, const int* in_sizes, int n_in,
                              void* d_out, int out_size, void* d_ws, size_t ws_size,
                              hipStream_t stream) {
    (void)in_sizes; (void)n_in; (void)out_size; (void)ws_size;
    const float* x  = (const float*)d_in[0];
    const float* W1 = (const float*)d_in[1];
    const float* W2 = (const float*)d_in[2];
    float* ws  = (float*)d_ws;
    float* out = (float*)d_out;

    // 1) K-major transposes of x, W1, W2
    transpose3<<<1280, 256, 0, stream>>>(x, W1, W2, ws);

    // 2) Layer 1: h^T partials [2][1024][512]; K=512 split 2x256
    morpho<false><<<dim3(16, 8, 2), 256, 0, stream>>>(
        ws + WS_XT, nullptr, ws + WS_W1T, ws + WS_HP, 1024, 256);

    // 3) Layer 2: A = max(hp0, hp1, 0) (fused relu); y^T partials [4][512][512];
    //    K=1024 split 4x256
    morpho<true><<<dim3(8, 8, 4), 256, 0, stream>>>(
        ws + WS_HP, ws + WS_HP + 1024 * 512, ws + WS_W2T, ws + WS_YP, 512, 256);

    // 4) Combine partials + relu + transpose -> d_out[b][o]
    combine4<<<256, 256, 0, stream>>>(ws + WS_YP, out);
}

// Round 2
// 97.389 us; speedup vs baseline: 1.1257x; 1.1257x over previous
//
#include <hip/hip_runtime.h>

// MorphoMLP: y = relu(maxplus(relu(maxplus(x,W1)), W2)), fp32.
// B=512, IN=512, HID=1024, OUT=512.
// R2: occupancy + LDS-ratio restructure.
//   transpose3 -> morpho2 L1 (128x64 tile, splitK=8, 512 blk) -> combineH
//   -> morpho2 L2 (splitK=16, 512 blk) -> combineY (max16 + relu + transpose)
// ws: xT 1MB | W1T 2MB | W2T 2MB | hp 16MB | A2 2MB | yp 16MB  = 39MB

#define WS_XT   0                          // [512][512]    x^T  [k][b]
#define WS_W1T  (512 * 512)                // [512][1024]   W1^T [k][j]
#define WS_W2T  (WS_W1T + 512 * 1024)      // [1024][512]   W2^T [k2][o]
#define WS_HP   (WS_W2T + 1024 * 512)      // [8][1024][512]  L1 partials
#define WS_A2   (WS_HP + 8 * 1024 * 512)   // [1024][512]   relu(h)^T [k2][b]
#define WS_YP   (WS_A2 + 1024 * 512)       // [16][512][512]  L2 partials

// ---------------------------------------------------------------------------
// Fused transpose of x (512x512), W1 (1024x512), W2 (512x1024) into ws.
__global__ __launch_bounds__(256) void transpose3(const float* __restrict__ x,
                                                  const float* __restrict__ W1,
                                                  const float* __restrict__ W2,
                                                  float* __restrict__ ws) {
    __shared__ float t[32][33];
    const int id = blockIdx.x;
    const float* src;
    float* dst;
    int R, C, rt, ct;
    if (id < 256) {
        src = x;  dst = ws + WS_XT;  R = 512;  C = 512;
        rt = id >> 4;          ct = id & 15;
    } else if (id < 768) {
        int b = id - 256;
        src = W1; dst = ws + WS_W1T; R = 1024; C = 512;
        rt = b >> 4;           ct = b & 15;
    } else {
        int b = id - 768;
        src = W2; dst = ws + WS_W2T; R = 512;  C = 1024;
        rt = b >> 5;           ct = b & 31;
    }
    const int tx = threadIdx.x & 31, ty = threadIdx.x >> 5;
    const int r0 = rt * 32, c0 = ct * 32;
#pragma unroll
    for (int r = 0; r < 4; r++)
        t[ty + 8 * r][tx] = src[(size_t)(r0 + ty + 8 * r) * C + c0 + tx];
    __syncthreads();
#pragma unroll
    for (int r = 0; r < 4; r++)
        dst[(size_t)(c0 + ty + 8 * r) * R + r0 + tx] = t[tx][ty + 8 * r];
}

// ---------------------------------------------------------------------------
// Max-plus tile kernel, single K-stage.
// A: [K][512] K-major activations; W: [K][JDIM] K-major weights.
// Block tile: 128 j x 64 b x 64 k. 256 threads, 8j x 4b fragment/thread.
// Stores raw partial (no relu) transposed: P[z][j][b].
template <int JDIM>
__global__ __launch_bounds__(256, 2) void morpho2(const float* __restrict__ A,
                                                  const float* __restrict__ W,
                                                  float* __restrict__ P) {
    __shared__ float lA[64 * 64];    // [k][b]  16KB
    __shared__ float lW[64 * 128];   // [k][j]  32KB
    const int t  = threadIdx.x;
    const int tx = t & 15;           // b frag: b0 + tx*4 + {0..3}
    const int ty = t >> 4;           // j frag: j0 + ty*8 + {0..7}
    const int j0 = blockIdx.x * 128;
    const int b0 = blockIdx.y * 64;
    const int k0 = blockIdx.z * 64;

    // ---- stage A tile: 1024 float4, 4/thread ----
#pragma unroll
    for (int r = 0; r < 4; r++) {
        const int q  = t + 256 * r;
        const int kk = q >> 4, c = q & 15;
        ((float4*)lA)[q] = *((const float4*)(A + (size_t)(k0 + kk) * 512 + b0) + c);
    }
    // ---- stage W tile: 2048 float4, 8/thread ----
#pragma unroll
    for (int r = 0; r < 8; r++) {
        const int q  = t + 256 * r;
        const int kk = q >> 5, c = q & 31;
        ((float4*)lW)[q] = *((const float4*)(W + (size_t)(k0 + kk) * JDIM + j0) + c);
    }
    __syncthreads();

    float acc[8][4];
#pragma unroll
    for (int jj = 0; jj < 8; jj++)
#pragma unroll
        for (int i = 0; i < 4; i++) acc[jj][i] = -3.402823466e38f;

    const float4* lA4 = (const float4*)lA;
    const float4* lW4 = (const float4*)lW;

    // ---- inner max-plus: 2 k's per iter so fmax pairs fuse to v_max3 ----
#pragma unroll 4
    for (int kk = 0; kk < 64; kk += 2) {
        const float4 a0  = lA4[kk * 16 + tx];
        const float4 a1  = lA4[kk * 16 + 16 + tx];
        const float4 w0a = lW4[kk * 32 + ty * 2];
        const float4 w0b = lW4[kk * 32 + ty * 2 + 1];
        const float4 w1a = lW4[kk * 32 + 32 + ty * 2];
        const float4 w1b = lW4[kk * 32 + 32 + ty * 2 + 1];
#define UPD(JJ, W0C, W1C)                                                  \
    acc[JJ][0] = fmaxf(fmaxf(acc[JJ][0], a0.x + (W0C)), a1.x + (W1C));     \
    acc[JJ][1] = fmaxf(fmaxf(acc[JJ][1], a0.y + (W0C)), a1.y + (W1C));     \
    acc[JJ][2] = fmaxf(fmaxf(acc[JJ][2], a0.z + (W0C)), a1.z + (W1C));     \
    acc[JJ][3] = fmaxf(fmaxf(acc[JJ][3], a0.w + (W0C)), a1.w + (W1C));
        UPD(0, w0a.x, w1a.x)
        UPD(1, w0a.y, w1a.y)
        UPD(2, w0a.z, w1a.z)
        UPD(3, w0a.w, w1a.w)
        UPD(4, w0b.x, w1b.x)
        UPD(5, w0b.y, w1b.y)
        UPD(6, w0b.z, w1b.z)
        UPD(7, w0b.w, w1b.w)
#undef UPD
    }

    // ---- store transposed partial: P[z][j][b], float4 over b (coalesced) ----
    float* Pp = P + (size_t)blockIdx.z * JDIM * 512;
#pragma unroll
    for (int jj = 0; jj < 8; jj++) {
        const float4 v = make_float4(acc[jj][0], acc[jj][1], acc[jj][2], acc[jj][3]);
        *(float4*)(Pp + (size_t)(j0 + ty * 8 + jj) * 512 + b0 + tx * 4) = v;
    }
}

// ---------------------------------------------------------------------------
// combineH: A2[j][b] = relu(max_z hp[z][j][b]).  Already K-major for L2.
// 512 blocks x 256 thr x 1 float4 = 512K floats.
__global__ __launch_bounds__(256) void combineH(const float* __restrict__ hp,
                                                float* __restrict__ A2) {
    const int i = blockIdx.x * 256 + threadIdx.x;   // float4 index
    const float4* p = (const float4*)hp;
    float4 m = p[i];
#pragma unroll
    for (int z = 1; z < 8; z++) {
        const float4 v = p[i + z * 131072];         // 512K floats / 4
        m.x = fmaxf(m.x, v.x);
        m.y = fmaxf(m.y, v.y);
        m.z = fmaxf(m.z, v.z);
        m.w = fmaxf(m.w, v.w);
    }
    m.x = fmaxf(m.x, 0.0f);
    m.y = fmaxf(m.y, 0.0f);
    m.z = fmaxf(m.z, 0.0f);
    m.w = fmaxf(m.w, 0.0f);
    ((float4*)A2)[i] = m;
}

// ---------------------------------------------------------------------------
// combineY: out[b][o] = relu(max_z yp[z][o][b]); 16 partials + transpose.
__global__ __launch_bounds__(256) void combineY(const float* __restrict__ yp,
                                                float* __restrict__ out) {
    __shared__ float t[32][33];
    const int id = blockIdx.x;
    const int ot = id & 15, bt = id >> 4;
    const int tx = threadIdx.x & 31, ty = threadIdx.x >> 5;
    const int o0 = ot * 32, b0 = bt * 32;
#pragma unroll
    for (int r = 0; r < 4; r++) {
        const int o   = o0 + ty + 8 * r;
        const int idx = o * 512 + b0 + tx;
        float m = yp[idx];
#pragma unroll
        for (int z = 1; z < 16; z++) m = fmaxf(m, yp[idx + z * 262144]);
        t[ty + 8 * r][tx] = fmaxf(m, 0.0f);
    }
    __syncthreads();
#pragma unroll
    for (int r = 0; r < 4; r++)
        out[(b0 + ty + 8 * r) * 512 + o0 + tx] = t[tx][ty + 8 * r];
}

// ---------------------------------------------------------------------------
extern "C" void kernel_launch(void* const* d_in, const int* in_sizes, int n_in,
                              void* d_out, int out_size, void* d_ws, size_t ws_size,
                              hipStream_t stream) {
    (void)in_sizes; (void)n_in; (void)out_size; (void)ws_size;
    const float* x  = (const float*)d_in[0];
    const float* W1 = (const float*)d_in[1];
    const float* W2 = (const float*)d_in[2];
    float* ws  = (float*)d_ws;
    float* out = (float*)d_out;

    // 1) K-major transposes of x, W1, W2
    transpose3<<<1280, 256, 0, stream>>>(x, W1, W2, ws);

    // 2) L1: hp[8][1024][512]; grid 8(j) x 8(b) x 8(kz), Kchunk=64
    morpho2<1024><<<dim3(8, 8, 8), 256, 0, stream>>>(
        ws + WS_XT, ws + WS_W1T, ws + WS_HP);

    // 3) combine 8 partials + relu -> A2[k2][b]
    combineH<<<512, 256, 0, stream>>>(ws + WS_HP, ws + WS_A2);

    // 4) L2: yp[16][512][512]; grid 4(j) x 8(b) x 16(kz), Kchunk=64
    morpho2<512><<<dim3(4, 8, 16), 256, 0, stream>>>(
        ws + WS_A2, ws + WS_W2T, ws + WS_YP);

    // 5) combine 16 partials + relu + transpose -> d_out[b][o]
    combineY<<<256, 256, 0, stream>>>(ws + WS_YP, out);
}